// Round 14
// baseline (902.500 us; speedup 1.0000x reference)
//
#include <hip/hip_runtime.h>
#include <hip/hip_fp16.h>

// NNUE forward, fully fused: out = MLP(clip(concat(Wf@w_in^T+b, Bf@w_in^T+b)))
// v12 (r13 post-mortem): every prior design had 65536 concurrent DRAM read
// streams (512 blocks x 128 rows, K-split x8 redundancy). This version:
// block = 16 batch rows (16 white + 16 black A-rows), FULL K walk ->
// 8192 streams, each row read once, linearly. The block ends holding
// x[16][512] -> whole MLP tail fused in-block; NO P workspace at all.
//  - 8 waves = (color ws, N-quarter wn); wave = 16 rows x 64 cols, acc 4xf4.
//  - A flatmm: global->VGPR->cvt->MFMA (4 wn-waves share rows; L1 absorbs).
//  - W: pre-swizzled f16 image (20 MB ws), global_load_lds, 8 x 16KB bufs,
//    4-step groups (320 barriers), vmcnt(8)+lgkmcnt(0) per group.
//  - phase window t0=(bid*5)%128 de-phases banks, keeps W L2-resident/XCD.
//  - LDS 148 KB: Ws 128K + xs[16][520] f16 + h1/h2.

#define FEAT 40960
#define NSTEP 1280
#define WTILE_BYTES 16384        // 256 rows x 32 k x f16, swizzled
#define WWS_BYTES ((size_t)NSTEP * WTILE_BYTES)   // 20 MB

using floatx4 = __attribute__((ext_vector_type(4))) float;
using half8   = __attribute__((ext_vector_type(8))) _Float16;

// ---------------------------------------------------------------------------
// W pre-pass: w_in f32 [256][40960] -> Wws f16, 1280 chunks of 16 KB; chunk T
// covers k [T*32, T*32+32): byte(r, g) = T*16384 + r*64 + ((g^((r>>1)&3))<<4).
// ---------------------------------------------------------------------------
__global__ __launch_bounds__(256) void nnue_wprep(
    const float* __restrict__ w_in, _Float16* __restrict__ Wws)
{
    const int T = blockIdx.x;                 // 0..1279
    char* base = (char*)Wws + (size_t)T * WTILE_BYTES;
    const int tid = threadIdx.x;
    const int kg0 = T * 32;
#pragma unroll
    for (int i = 0; i < 4; ++i) {
        const int G = tid + i * 256;          // 0..1023
        const int r = G >> 2, g = G & 3;
        const float* src = w_in + (size_t)r * FEAT + kg0 + g * 8;
        floatx4 v0 = *reinterpret_cast<const floatx4*>(src);
        floatx4 v1 = *reinterpret_cast<const floatx4*>(src + 4);
        half8 h;
#pragma unroll
        for (int j = 0; j < 4; ++j) { h[j] = (_Float16)v0[j]; h[4 + j] = (_Float16)v1[j]; }
        *reinterpret_cast<half8*>(base + r * 64 + ((g ^ ((r >> 1) & 3)) << 4)) = h;
    }
}

// ---------------------------------------------------------------------------
// Fused GEMM + MLP. 512 thr = 8 waves; grid = 256 (one block per 16 batch).
// ---------------------------------------------------------------------------
__global__ __launch_bounds__(512, 2) void nnue_fused(
    const float* __restrict__ white, const float* __restrict__ black,
    const _Float16* __restrict__ Wws,
    const float* __restrict__ b_in,
    const float* __restrict__ w_h1, const float* __restrict__ b_h1,
    const float* __restrict__ w_h2, const float* __restrict__ b_h2,
    const float* __restrict__ w_out, const float* __restrict__ b_out,
    float* __restrict__ out)
{
    __shared__ __align__(16) _Float16 Ws[8][256 * 32];   // 128 KB
    __shared__ _Float16 xs[16][520];                     // 16.6 KB (pad: 2-way)
    __shared__ float h1s[16][33];
    __shared__ float h2s[16][33];

    const int tid  = threadIdx.x;
    const int lane = tid & 63;
    const int wave = tid >> 6;    // 0..7
    const int ws   = wave >> 2;   // 0=white, 1=black
    const int wn   = wave & 3;    // N-quarter (64 cols)

    const int b0 = blockIdx.x * 16;          // batch rows b0..b0+15

    const int frow = lane & 15;
    const int fhi  = lane >> 4;

    // A: lane's row = b0+frow of its color; tile t covers k = t*32, lane
    // reads 8 consecutive floats at k + fhi*8 (matches MFMA A-fragment).
    const float* Abase = (ws ? black : white) + (size_t)(b0 + frow) * FEAT + fhi * 8;

    // W LDS read: bf[n] at row r = wn*64+n*16+frow, byte = r*64 + kb
    const int kb = (fhi * 16) ^ (((frow >> 1) & 3) << 4);

    // W async staging: per-lane global src (pre-swizzled), wave-linear LDS
    const char* wsrc0 = (const char*)Wws + wave * 2048 + lane * 16;

    // phase window: de-phase DRAM banks, keep W window (128 tiles = 2 MB)
    // L2-resident per XCD.
    const int t0 = (blockIdx.x * 5) % 128;
    auto wrap = [](int x) { return (x >= NSTEP) ? x - NSTEP : x; };

    floatx4 acc[4];
    const floatx4 zero = {0.f, 0.f, 0.f, 0.f};
#pragma unroll
    for (int n = 0; n < 4; ++n) acc[n] = zero;

    floatx4 cA[8], nA[8];   // two group-sized A prefetch sets (const-idx only)

    auto issueW = [&](int t, int buf) {
        const char* g = wsrc0 + (size_t)t * WTILE_BYTES;
        char* l = (char*)&Ws[buf][0] + wave * 2048;
        __builtin_amdgcn_global_load_lds(
            (const __attribute__((address_space(1))) unsigned int*)g,
            (__attribute__((address_space(3))) unsigned int*)l, 16, 0, 0);
        __builtin_amdgcn_global_load_lds(
            (const __attribute__((address_space(1))) unsigned int*)(g + 1024),
            (__attribute__((address_space(3))) unsigned int*)(l + 1024), 16, 0, 0);
    };

    auto issueW4 = [&](int p0, int p1, int p2, int p3, int bb) {
        issueW(p0, bb); issueW(p1, bb + 1); issueW(p2, bb + 2); issueW(p3, bb + 3);
    };

    auto loadA4 = [&](floatx4 (&ra)[8], int p0, int p1, int p2, int p3) {
        ra[0] = *reinterpret_cast<const floatx4*>(Abase + (size_t)p0 * 32);
        ra[1] = *reinterpret_cast<const floatx4*>(Abase + (size_t)p0 * 32 + 4);
        ra[2] = *reinterpret_cast<const floatx4*>(Abase + (size_t)p1 * 32);
        ra[3] = *reinterpret_cast<const floatx4*>(Abase + (size_t)p1 * 32 + 4);
        ra[4] = *reinterpret_cast<const floatx4*>(Abase + (size_t)p2 * 32);
        ra[5] = *reinterpret_cast<const floatx4*>(Abase + (size_t)p2 * 32 + 4);
        ra[6] = *reinterpret_cast<const floatx4*>(Abase + (size_t)p3 * 32);
        ra[7] = *reinterpret_cast<const floatx4*>(Abase + (size_t)p3 * 32 + 4);
    };

    auto cvt = [&](const floatx4& a0, const floatx4& a1) {
        half8 h;
#pragma unroll
        for (int j = 0; j < 4; ++j) { h[j] = (_Float16)a0[j]; h[4 + j] = (_Float16)a1[j]; }
        return h;
    };

    auto mfma4 = [&](int bb, floatx4 (&ra)[8]) {
#pragma unroll
        for (int s = 0; s < 4; ++s) {
            half8 af = cvt(ra[2 * s], ra[2 * s + 1]);
            const char* wbase = (const char*)&Ws[bb + s][0];
#pragma unroll
            for (int n = 0; n < 4; ++n) {
                const int r = wn * 64 + n * 16 + frow;
                half8 bf = *reinterpret_cast<const half8*>(wbase + r * 64 + kb);
                acc[n] = __builtin_amdgcn_mfma_f32_16x16x32_f16(af, bf, acc[n], 0, 0, 0);
            }
        }
    };

    // group: consume 4 tiles (A in cc, W bufs rb..rb+3), prefetch next 4
    // (wrapped indices) into wb..wb+3 and nn.
    auto grp = [&](int p0, int p1, int p2, int p3,
                   floatx4 (&cc)[8], floatx4 (&nn)[8], int rb, int wb) {
        issueW4(p0, p1, p2, p3, wb);
        __builtin_amdgcn_sched_barrier(0);
        loadA4(nn, p0, p1, p2, p3);
        mfma4(rb, cc);                          // cvt waits cc: counted vmcnt
        // retire this group's 8 W (LDS visibility); keep the 8 A in flight.
        asm volatile("s_waitcnt vmcnt(8) lgkmcnt(0)" ::: "memory");
        __builtin_amdgcn_s_barrier();
        __builtin_amdgcn_sched_barrier(0);
    };

    // prologue: tiles t0..t0+3 -> bufs 0-3 retired; their A in cA (in flight)
    {
        const int p0 = t0, p1 = wrap(t0 + 1), p2 = wrap(t0 + 2), p3 = wrap(t0 + 3);
        issueW4(p0, p1, p2, p3, 0);
        __builtin_amdgcn_sched_barrier(0);
        loadA4(cA, p0, p1, p2, p3);
        asm volatile("s_waitcnt vmcnt(8)" ::: "memory");   // W retired, A kept
        __builtin_amdgcn_s_barrier();
        __builtin_amdgcn_sched_barrier(0);
    }

    // main: 159 pairs = groups 0..317, then group 318, then tail group 319
    for (int p = 0; p < 159; ++p) {
        const int i0 = 8 * p;
        grp(wrap(t0 + i0 + 4), wrap(t0 + i0 + 5), wrap(t0 + i0 + 6), wrap(t0 + i0 + 7),
            cA, nA, 0, 4);
        grp(wrap(t0 + i0 + 8), wrap(t0 + i0 + 9), wrap(t0 + i0 + 10), wrap(t0 + i0 + 11),
            nA, cA, 4, 0);
    }
    // group 318: consume tiles 1272-1275 (bufs 0-3), prefetch 1276-1279
    grp(wrap(t0 + 1276), wrap(t0 + 1277), wrap(t0 + 1278), wrap(t0 + 1279),
        cA, nA, 0, 4);
    // tail group 319: consume tiles 1276-1279 (bufs 4-7)
    mfma4(4, nA);
    asm volatile("s_waitcnt vmcnt(0) lgkmcnt(0)" ::: "memory");
    __builtin_amdgcn_s_barrier();
    __builtin_amdgcn_sched_barrier(0);

    // ---- epilogue: x = clip(acc + b_in) -> xs (f16), then the MLP tail ----
#pragma unroll
    for (int n = 0; n < 4; ++n) {
        const int bcol = wn * 64 + n * 16 + frow;     // w_in output index
        const float bi = b_in[bcol];
#pragma unroll
        for (int r = 0; r < 4; ++r) {
            const int row = fhi * 4 + r;              // batch row within block
            xs[row][ws * 256 + bcol] = (_Float16)fminf(fmaxf(acc[n][r] + bi, 0.f), 1.f);
        }
    }
    __syncthreads();

    // h1 = clip(x @ w_h1^T + b_h1): 16 rows x 32 outs = 512 dots (1/thread)
    {
        const int r = tid >> 5, o = tid & 31;
        float a = b_h1[o];
        const float* wrow = w_h1 + o * 512;
#pragma unroll 8
        for (int j = 0; j < 512; ++j) a += (float)xs[r][j] * wrow[j];
        h1s[r][o] = fminf(fmaxf(a, 0.f), 1.f);
    }
    __syncthreads();

    // h2 = clip(h1 @ w_h2^T + b_h2)
    {
        const int r = tid >> 5, o = tid & 31;
        float a = b_h2[o];
#pragma unroll
        for (int j = 0; j < 32; ++j) a += h1s[r][j] * w_h2[o * 32 + j];
        h2s[r][o] = fminf(fmaxf(a, 0.f), 1.f);
    }
    __syncthreads();

    // out = h2 @ w_out^T + b_out
    if (tid < 16) {
        float a = b_out[0];
#pragma unroll
        for (int j = 0; j < 32; ++j) a += h2s[tid][j] * w_out[j];
        out[b0 + tid] = a;
    }
}

// ---------------------------------------------------------------------------
// Emergency fallback (ws too small for the 20 MB W image): slow but correct.
// ---------------------------------------------------------------------------
__global__ __launch_bounds__(256) void nnue_naive(
    const float* __restrict__ white, const float* __restrict__ black,
    const float* __restrict__ w_in, const float* __restrict__ b_in,
    const float* __restrict__ w_h1, const float* __restrict__ b_h1,
    const float* __restrict__ w_h2, const float* __restrict__ b_h2,
    const float* __restrict__ w_out, const float* __restrict__ b_out,
    float* __restrict__ out)
{
    __shared__ float feat[4096];
    __shared__ float xsv[512];
    __shared__ float h1s[32];
    __shared__ float h2s[32];
    const int b = blockIdx.x, tid = threadIdx.x;
    float acc0 = 0.f, acc1 = 0.f;
    for (int c = 0; c < FEAT; c += 2048) {
        for (int i = tid; i < 2048; i += 256) {
            feat[i]        = white[(size_t)b * FEAT + c + i];
            feat[2048 + i] = black[(size_t)b * FEAT + c + i];
        }
        __syncthreads();
        const float* wr = w_in + (size_t)tid * FEAT + c;
        for (int k = 0; k < 2048; ++k) {
            const float w = wr[k];
            acc0 += feat[k] * w;
            acc1 += feat[2048 + k] * w;
        }
        __syncthreads();
    }
    xsv[tid]       = fminf(fmaxf(acc0 + b_in[tid], 0.f), 1.f);
    xsv[256 + tid] = fminf(fmaxf(acc1 + b_in[tid], 0.f), 1.f);
    __syncthreads();
    if (tid < 32) {
        float a = b_h1[tid];
        for (int j = 0; j < 512; ++j) a += xsv[j] * w_h1[tid * 512 + j];
        h1s[tid] = fminf(fmaxf(a, 0.f), 1.f);
    }
    __syncthreads();
    if (tid < 32) {
        float a = b_h2[tid];
        for (int j = 0; j < 32; ++j) a += h1s[j] * w_h2[tid * 32 + j];
        h2s[tid] = fminf(fmaxf(a, 0.f), 1.f);
    }
    __syncthreads();
    if (tid == 0) {
        float a = b_out[0];
        for (int j = 0; j < 32; ++j) a += h2s[j] * w_out[j];
        out[b] = a;
    }
}

extern "C" void kernel_launch(void* const* d_in, const int* in_sizes, int n_in,
                              void* d_out, int out_size, void* d_ws, size_t ws_size,
                              hipStream_t stream)
{
    const float* white = (const float*)d_in[0];
    const float* black = (const float*)d_in[1];
    const float* w_in  = (const float*)d_in[2];
    const float* b_in  = (const float*)d_in[3];
    const float* w_h1  = (const float*)d_in[4];
    const float* b_h1  = (const float*)d_in[5];
    const float* w_h2  = (const float*)d_in[6];
    const float* b_h2  = (const float*)d_in[7];
    const float* w_out = (const float*)d_in[8];
    const float* b_out = (const float*)d_in[9];
    float* out = (float*)d_out;

    if (ws_size >= WWS_BYTES) {
        _Float16* Wws = (_Float16*)d_ws;
        nnue_wprep<<<dim3(NSTEP), 256, 0, stream>>>(w_in, Wws);
        nnue_fused<<<dim3(256), 512, 0, stream>>>(white, black, Wws, b_in,
                                                  w_h1, b_h1, w_h2, b_h2,
                                                  w_out, b_out, out);
    } else {
        nnue_naive<<<4096, 256, 0, stream>>>(white, black, w_in, b_in, w_h1, b_h1,
                                             w_h2, b_h2, w_out, b_out, out);
    }
}

// Round 15
// 389.142 us; speedup vs baseline: 2.3192x; 2.3192x over previous
//
#include <hip/hip_runtime.h>
#include <hip/hip_fp16.h>

// NNUE forward: out = MLP(clip(concat(Wf@w_in^T+b, Bf@w_in^T+b)))
// Big GEMM: M=8192, N=256, K=40960, HBM-bound on the 1.31 GB A stream.
// fp16 MFMA 16x16x32, f32 accumulate.
//
// v13 = v11 + NON-TEMPORAL A loads (single lever).
// r14 post-mortem: v12 (fused, M=16/block) moved 2.4x the bytes -> 902us;
// W amortization requires M>=128/block. v11 (372us) kept as base.
// Theory: the zero-reuse A stream floods each XCD's 4MB L2 ~40x over the
// kernel, evicting the W chunk that 64 blocks share -> W re-fetches from
// L3/HBM and long waits at each vmcnt(4) barrier (the ~2000cyc/interval
// residue). __builtin_nontemporal_load on A ("nt": no L2 allocate /
// evict-first) leaves L2 to W. A has zero reuse -> no downside.
// Everything else identical to v11: flatmm, 2 tiles/barrier, 4 W bufs,
// K-rotation t0=(mb*37)%160, KS=8 -> 512 blocks 2/CU, ks=blockIdx&7=XCD.

#define FEAT 40960
#define PSTRIDE (8192ull * 256ull)
#define KSPLIT 8
#define KCHUNK (FEAT / KSPLIT)   // 5120
#define NSTEP 160
#define WTILE_BYTES 16384        // 256 rows x 32 k x f16, swizzled
#define WWS_BYTES (1280ull * WTILE_BYTES)   // 20 MB

using floatx4 = __attribute__((ext_vector_type(4))) float;
using half8   = __attribute__((ext_vector_type(8))) _Float16;

__device__ __forceinline__ floatx4 ldnt(const float* p) {
    return __builtin_nontemporal_load(reinterpret_cast<const floatx4*>(p));
}

// ---------------------------------------------------------------------------
// W pre-pass: w_in f32 [256][40960] -> Wws f16, 1280 chunks of 16 KB, each
// the exact swizzled LDS image for one K-step: byte(r, granule g) =
// T*16384 + r*64 + ((g ^ ((r>>1)&3))*16). T = ks*160 + t (ks-major).
// ---------------------------------------------------------------------------
__global__ __launch_bounds__(256) void nnue_wprep(
    const float* __restrict__ w_in, _Float16* __restrict__ Wws)
{
    const int bid = blockIdx.x;                       // 1280
    const int T   = (bid & 7) * NSTEP + (bid >> 3);
    char* base = (char*)Wws + (size_t)T * WTILE_BYTES;
    const int tid = threadIdx.x;
    const int kg0 = T * 32;
#pragma unroll
    for (int i = 0; i < 4; ++i) {
        const int G = tid + i * 256;                  // 0..1023
        const int r = G >> 2, g = G & 3;
        const float* src = w_in + (size_t)r * FEAT + kg0 + g * 8;
        floatx4 v0 = *reinterpret_cast<const floatx4*>(src);
        floatx4 v1 = *reinterpret_cast<const floatx4*>(src + 4);
        half8 h;
#pragma unroll
        for (int j = 0; j < 4; ++j) { h[j] = (_Float16)v0[j]; h[4 + j] = (_Float16)v1[j]; }
        *reinterpret_cast<half8*>(base + r * 64 + ((g ^ ((r >> 1) & 3)) << 4)) = h;
    }
}

// ---------------------------------------------------------------------------
// Primary GEMM: 512 thr = 8 waves, wave strip = 16 rows x 256 cols.
// ---------------------------------------------------------------------------
template <typename PT>
__global__ __launch_bounds__(512, 4) void nnue_gemm_v13(
    const float* __restrict__ white, const float* __restrict__ black,
    const _Float16* __restrict__ Wws, PT* __restrict__ P)
{
    __shared__ __align__(16) _Float16 Ws[4][256 * 32];   // 64 KB

    const int tid  = threadIdx.x;
    const int lane = tid & 63;
    const int wave = tid >> 6;    // 0..7

    const int ks = blockIdx.x & 7;    // == XCD index (round-robin dispatch)
    const int mb = blockIdx.x >> 3;   // 0..63

    const float* Abase = (mb < 32)
        ? (white + (size_t)mb * 128 * FEAT)
        : (black + (size_t)(mb - 32) * 128 * FEAT);

    // K-rotation phase: de-alias DRAM channels across blocks.
    const int t0 = (mb * 37) % NSTEP;
    auto wrap = [](int x) { return (x >= NSTEP) ? x - NSTEP : x; };  // x < 2*NSTEP

    const int frow = lane & 15;
    const int fhi  = lane >> 4;

    // A: per-lane row = wave*16 + frow; tile t covers k = ks*KCHUNK + t*32
    const float* Aptr = Abase + (size_t)(wave * 16 + frow) * FEAT + fhi * 8
                        + ks * KCHUNK;

    // W LDS read byte offset within a row: (fhi*16) ^ (((frow>>1)&3)<<4)
    const int kb = (fhi * 16) ^ (((frow >> 1) & 3) << 4);

    // W async staging: per-lane global src (pre-swizzled), wave-linear LDS
    const char* wsrc0 = (const char*)Wws + (size_t)(ks * NSTEP) * WTILE_BYTES
                        + wave * 2048 + lane * 16;

    floatx4 acc[16];
    const floatx4 zero = {0.f, 0.f, 0.f, 0.f};
#pragma unroll
    for (int n = 0; n < 16; ++n) acc[n] = zero;

    // two statically-named A prefetch sets, each = one GROUP (2 tiles)
    floatx4 cA0, cA1, cA2, cA3, nA0, nA1, nA2, nA3;

    auto issueW = [&](int t, int wb) {               // t = wrapped tile index
        const char* g = wsrc0 + (size_t)t * WTILE_BYTES;
        char* l = (char*)&Ws[wb][0] + wave * 2048;
        __builtin_amdgcn_global_load_lds(
            (const __attribute__((address_space(1))) unsigned int*)g,
            (__attribute__((address_space(3))) unsigned int*)l, 16, 0, 0);
        __builtin_amdgcn_global_load_lds(
            (const __attribute__((address_space(1))) unsigned int*)(g + 1024),
            (__attribute__((address_space(3))) unsigned int*)(l + 1024), 16, 0, 0);
    };

    auto cvt = [&](const floatx4& a0, const floatx4& a1) {
        half8 h;
#pragma unroll
        for (int j = 0; j < 4; ++j) { h[j] = (_Float16)a0[j]; h[4 + j] = (_Float16)a1[j]; }
        return h;
    };

    auto mfmaStep = [&](int wb, half8 af) {
        const char* wbase = (const char*)&Ws[wb][0];
#pragma unroll
        for (int n = 0; n < 16; ++n) {
            half8 bf = *reinterpret_cast<const half8*>(
                wbase + (n * 16 + frow) * 64 + kb);
            acc[n] = __builtin_amdgcn_mfma_f32_16x16x32_f16(af, bf, acc[n], 0, 0, 0);
        }
    };

    // one group: consume 2 tiles (A in c*, W in rb0/rb1), prefetch the next
    // group's 2 tiles (tw0, tw1 wrapped) into wb0/wb1 and n*.
    auto groupf = [&](int tw0, int tw1,
                      floatx4& c0, floatx4& c1, floatx4& c2, floatx4& c3,
                      floatx4& n0, floatx4& n1, floatx4& n2, floatx4& n3,
                      int rb0, int rb1, int wb0, int wb1) {
        issueW(tw0, wb0);
        issueW(tw1, wb1);
        __builtin_amdgcn_sched_barrier(0);
        n0 = ldnt(Aptr + (size_t)tw0 * 32);
        n1 = ldnt(Aptr + (size_t)tw0 * 32 + 4);
        n2 = ldnt(Aptr + (size_t)tw1 * 32);
        n3 = ldnt(Aptr + (size_t)tw1 * 32 + 4);
        mfmaStep(rb0, cvt(c0, c1));            // cvt waits its A: counted vmcnt
        mfmaStep(rb1, cvt(c2, c3));
        // retire this group's W (cross-wave LDS visibility after the barrier);
        // keep the 4 A loads in flight across the barrier.
        asm volatile("s_waitcnt vmcnt(4) lgkmcnt(0)" ::: "memory");
        __builtin_amdgcn_s_barrier();
        __builtin_amdgcn_sched_barrier(0);
    };

    // prologue: tiles i=0,1 (wrapped) -> bufs 0,1 retired; their A in regs
    {
        const int p0 = t0;                 // wrap(t0) == t0
        const int p1 = wrap(t0 + 1);
        issueW(p0, 0);
        issueW(p1, 1);
        __builtin_amdgcn_sched_barrier(0);
        cA0 = ldnt(Aptr + (size_t)p0 * 32);
        cA1 = ldnt(Aptr + (size_t)p0 * 32 + 4);
        cA2 = ldnt(Aptr + (size_t)p1 * 32);
        cA3 = ldnt(Aptr + (size_t)p1 * 32 + 4);
        asm volatile("s_waitcnt vmcnt(4)" ::: "memory");   // W(i0),W(i1) retired
        __builtin_amdgcn_s_barrier();
        __builtin_amdgcn_sched_barrier(0);
    }

    // groups 0..77 (39 even/odd pairs); group g prefetches iterations 2g+2,2g+3
    for (int p = 0; p < 39; ++p) {
        const int i0 = 4 * p;
        groupf(wrap(t0 + i0 + 2), wrap(t0 + i0 + 3),
               cA0, cA1, cA2, cA3, nA0, nA1, nA2, nA3, 0, 1, 2, 3);
        groupf(wrap(t0 + i0 + 4), wrap(t0 + i0 + 5),
               nA0, nA1, nA2, nA3, cA0, cA1, cA2, cA3, 2, 3, 0, 1);
    }
    // group 78: reads bufs 0,1 (iters 156,157); prefetch iters 158,159
    groupf(wrap(t0 + 158), wrap(t0 + 159),
           cA0, cA1, cA2, cA3, nA0, nA1, nA2, nA3, 0, 1, 2, 3);
    // group 79 tail: iters 158 (buf 2), 159 (buf 3)
    mfmaStep(2, cvt(nA0, nA1));
    mfmaStep(3, cvt(nA2, nA3));

    // epilogue: partial C. row = wave*16 + fhi*4 + r, col = n*16 + frow
    PT* Pb = P + (size_t)ks * PSTRIDE + (size_t)mb * 128 * 256;
#pragma unroll
    for (int n = 0; n < 16; ++n)
#pragma unroll
        for (int r = 0; r < 4; ++r) {
            const int row = wave * 16 + fhi * 4 + r;
            const int col = n * 16 + frow;
            Pb[(size_t)row * 256 + col] = (PT)acc[n][r];
        }
}

// ---------------------------------------------------------------------------
// Tail: reduce KS partials + b_in + clip -> x[.,512], then the 3 tiny layers.
// One block per 32 batch rows.
// ---------------------------------------------------------------------------
template <typename PT>
__global__ __launch_bounds__(256) void nnue_tail(
    const PT* __restrict__ P,
    const float* __restrict__ b_in,
    const float* __restrict__ w_h1, const float* __restrict__ b_h1,
    const float* __restrict__ w_h2, const float* __restrict__ b_h2,
    const float* __restrict__ w_out, const float* __restrict__ b_out,
    float* __restrict__ out)
{
    __shared__ float xs[32][512];
    __shared__ float w1[32][513];
    __shared__ float w2[32][33];
    __shared__ float h1[32][33];
    __shared__ float h2[32][33];
    __shared__ float wo[32];

    const int tid = threadIdx.x;
    const int b0  = blockIdx.x * 32;

    for (int i = tid; i < 32 * 512; i += 256) w1[i >> 9][i & 511] = w_h1[i];
    for (int i = tid; i < 32 * 32; i += 256)  w2[i >> 5][i & 31]  = w_h2[i];
    if (tid < 32) wo[tid] = w_out[tid];

    for (int i = tid; i < 32 * 512; i += 256) {
        const int r = i >> 9, c = i & 511;
        const int persp = c >> 8, n = c & 255;
        const size_t prow = (size_t)(b0 + r) + (persp ? 4096u : 0u);
        float v = 0.f;
#pragma unroll
        for (int s = 0; s < KSPLIT; ++s)
            v += (float)P[(size_t)s * PSTRIDE + prow * 256 + n];
        v += b_in[n];
        xs[r][c] = fminf(fmaxf(v, 0.f), 1.f);
    }
    __syncthreads();

    for (int p = tid; p < 32 * 32; p += 256) {
        const int o = p & 31, r = p >> 5;
        float a = b_h1[o];
        for (int j = 0; j < 512; ++j) a += xs[r][j] * w1[o][j];
        h1[r][o] = fminf(fmaxf(a, 0.f), 1.f);
    }
    __syncthreads();

    for (int p = tid; p < 32 * 32; p += 256) {
        const int o = p & 31, r = p >> 5;
        float a = b_h2[o];
        for (int j = 0; j < 32; ++j) a += h1[r][j] * w2[o][j];
        h2[r][o] = fminf(fmaxf(a, 0.f), 1.f);
    }
    __syncthreads();

    if (tid < 32) {
        float a = b_out[0];
        for (int j = 0; j < 32; ++j) a += h2[tid][j] * wo[j];
        out[b0 + tid] = a;
    }
}

// ---------------------------------------------------------------------------
// Emergency fallback (ws too small): slow but correct, no scratch.
// ---------------------------------------------------------------------------
__global__ __launch_bounds__(256) void nnue_naive(
    const float* __restrict__ white, const float* __restrict__ black,
    const float* __restrict__ w_in, const float* __restrict__ b_in,
    const float* __restrict__ w_h1, const float* __restrict__ b_h1,
    const float* __restrict__ w_h2, const float* __restrict__ b_h2,
    const float* __restrict__ w_out, const float* __restrict__ b_out,
    float* __restrict__ out)
{
    __shared__ float feat[4096];
    __shared__ float xs[512];
    __shared__ float h1s[32];
    __shared__ float h2s[32];
    const int b = blockIdx.x, tid = threadIdx.x;
    float acc0 = 0.f, acc1 = 0.f;
    for (int c = 0; c < FEAT; c += 2048) {
        for (int i = tid; i < 2048; i += 256) {
            feat[i]        = white[(size_t)b * FEAT + c + i];
            feat[2048 + i] = black[(size_t)b * FEAT + c + i];
        }
        __syncthreads();
        const float* wr = w_in + (size_t)tid * FEAT + c;
        for (int k = 0; k < 2048; ++k) {
            const float w = wr[k];
            acc0 += feat[k] * w;
            acc1 += feat[2048 + k] * w;
        }
        __syncthreads();
    }
    xs[tid]       = fminf(fmaxf(acc0 + b_in[tid], 0.f), 1.f);
    xs[256 + tid] = fminf(fmaxf(acc1 + b_in[tid], 0.f), 1.f);
    __syncthreads();
    if (tid < 32) {
        float a = b_h1[tid];
        for (int j = 0; j < 512; ++j) a += xs[j] * w_h1[tid * 512 + j];
        h1s[tid] = fminf(fmaxf(a, 0.f), 1.f);
    }
    __syncthreads();
    if (tid < 32) {
        float a = b_h2[tid];
        for (int j = 0; j < 32; ++j) a += h1s[j] * w_h2[tid * 32 + j];
        h2s[tid] = fminf(fmaxf(a, 0.f), 1.f);
    }
    __syncthreads();
    if (tid == 0) {
        float a = b_out[0];
        for (int j = 0; j < 32; ++j) a += h2s[j] * w_out[j];
        out[b] = a;
    }
}

extern "C" void kernel_launch(void* const* d_in, const int* in_sizes, int n_in,
                              void* d_out, int out_size, void* d_ws, size_t ws_size,
                              hipStream_t stream)
{
    const float* white = (const float*)d_in[0];
    const float* black = (const float*)d_in[1];
    const float* w_in  = (const float*)d_in[2];
    const float* b_in  = (const float*)d_in[3];
    const float* w_h1  = (const float*)d_in[4];
    const float* b_h1  = (const float*)d_in[5];
    const float* w_h2  = (const float*)d_in[6];
    const float* b_h2  = (const float*)d_in[7];
    const float* w_out = (const float*)d_in[8];
    const float* b_out = (const float*)d_in[9];
    float* out = (float*)d_out;

    const size_t pF32 = KSPLIT * PSTRIDE * sizeof(float);     // 64 MB
    const size_t pF16 = KSPLIT * PSTRIDE * sizeof(_Float16);  // 32 MB

    if (ws_size >= pF32 + WWS_BYTES) {
        float* P = (float*)d_ws;
        _Float16* Wws = (_Float16*)((char*)d_ws + pF32);
        nnue_wprep<<<dim3(1280), 256, 0, stream>>>(w_in, Wws);
        nnue_gemm_v13<float><<<dim3(512), 512, 0, stream>>>(white, black, Wws, P);
        nnue_tail<float><<<dim3(128), 256, 0, stream>>>(P, b_in, w_h1, b_h1,
                                                        w_h2, b_h2, w_out, b_out, out);
    } else if (ws_size >= pF16 + WWS_BYTES) {
        _Float16* P = (_Float16*)d_ws;
        _Float16* Wws = (_Float16*)((char*)d_ws + pF16);
        nnue_wprep<<<dim3(1280), 256, 0, stream>>>(w_in, Wws);
        nnue_gemm_v13<_Float16><<<dim3(512), 512, 0, stream>>>(white, black, Wws, P);
        nnue_tail<_Float16><<<dim3(128), 256, 0, stream>>>(P, b_in, w_h1, b_h1,
                                                           w_h2, b_h2, w_out, b_out, out);
    } else {
        nnue_naive<<<4096, 256, 0, stream>>>(white, black, w_in, b_in, w_h1, b_h1,
                                             w_h2, b_h2, w_out, b_out, out);
    }
}